// Round 2
// baseline (27959.497 us; speedup 1.0000x reference)
//
#include <hip/hip_runtime.h>
#include <math.h>
#include <float.h>

// Pointer-network decoder, 1024 sequential steps.
// R2 design: zero atomic-RMW. Per step, each of 256 blocks publishes one
// 32-B mailbox line {4 h-values, partial softmax/argmax triple, tag} and
// acquire-polls the other 255. All weights (24.6 MB) are held permanently
// in VGPRs (96 floats/thread x 65536 threads). visited is 4 local bits per
// block (every block redundantly reduces the global argmax).

#define SEQ   1024
#define FEAT  256
#define HID   1024
#define NB    256
#define TPB   256
#define AGENT __HIP_MEMORY_SCOPE_AGENT

typedef unsigned long long u64;
typedef unsigned int       u32;

struct alignas(32) Mbox {          // one 32-B line per block per parity
  u64 q[4];  // q0=(h0,h1) q1=(h2,h3) q2=(esum,best) q3=(idx | tag<<32)
};

__device__ __forceinline__ u64 pack_ff(float a, float b) {
  return (u64)__float_as_uint(a) | ((u64)__float_as_uint(b) << 32);
}
__device__ __forceinline__ float lo_f(u64 d) { return __uint_as_float((u32)d); }
__device__ __forceinline__ float hi_f(u64 d) { return __uint_as_float((u32)(d >> 32)); }

extern "C" __global__ void __launch_bounds__(TPB, 2)
decoder_main(const float* __restrict__ X,      // (SEQ, FEAT)
             const float* __restrict__ ENC,    // (SEQ, HID)
             const float* __restrict__ W_ih,   // (4H, FEAT)
             const float* __restrict__ W_hh,   // (4H, HID)
             const float* __restrict__ b_ih,
             const float* __restrict__ b_hh,
             const float* __restrict__ W_out,  // (OUT, HID)
             const float* __restrict__ b_out,
             float* __restrict__ out,          // [idx(1024) | logp(1024)] as f32
             Mbox* __restrict__ mb)            // [2][NB]
{
  const int b   = blockIdx.x;
  const int tid = threadIdx.x;
  const int wv  = tid >> 6;          // wave 0..3  == local h/logit row
  const int r   = tid >> 4;          // gate-row 0..15 (phase A)
  const int j   = tid & 15;          // phase-A lane within row
  const int l   = tid & 63;          // phase-B lane within wave
  const int gate = r & 3;            // i,f,g,o
  const int hrow = b * 4 + (r >> 2); // phase-A h row (== b*4+wv)
  const int grow = gate * HID + hrow;
  const int orow = b * 4 + wv;       // phase-B logit row

  __shared__ float4 h_lds[HID / 4];  // current h (4 KB)
  __shared__ float  h_new[4];
  __shared__ float  lg_e[4], lg_b[4];
  __shared__ float  cw_s[4], cw_b[4];
  __shared__ int    cw_i[4];
  __shared__ u32    vis;             // visited bits for this block's 4 rows

  // ---- one-time: weights into registers (exactly 96 floats/thread) ----
  const float4* WHH  = (const float4*)W_hh;
  const float4* WIH  = (const float4*)W_ih;
  const float4* WOUT = (const float4*)W_out;
  const float4* X4   = (const float4*)X;
  float4 wh[16], wi[4], wo[4];
  #pragma unroll
  for (int m = 0; m < 16; ++m) wh[m] = WHH[(size_t)grow * 256 + j + 16 * m];
  #pragma unroll
  for (int m = 0; m < 4; ++m)  wi[m] = WIH[(size_t)grow * 64 + j + 16 * m];
  #pragma unroll
  for (int m = 0; m < 4; ++m)  wo[m] = WOUT[(size_t)orow * 256 + l + 64 * m];
  const float bias_g = b_ih[grow] + b_hh[grow];
  const float bias_o = b_out[orow];                       // used by l==0
  const float c0     = ENC[(size_t)(SEQ - 1) * HID + hrow]; // used by l==0

  for (int i = tid; i < HID / 4; i += TPB) h_lds[i] = make_float4(0.f, 0.f, 0.f, 0.f);
  if (tid == 0) vis = 0u;
  __syncthreads();

  for (int k = 0; k <= SEQ; ++k) {
    // prefetch x_k slice early (hides under phase B)
    float4 xv0, xv1, xv2, xv3;
    if (k < SEQ) {
      const float4* xr = X4 + (size_t)k * 64;
      xv0 = xr[j]; xv1 = xr[j + 16]; xv2 = xr[j + 32]; xv3 = xr[j + 48];
    }

    // ---- Phase B: partials of logits(k-1) from h_{k-1} in LDS ----
    if (k > 0) {
      float4 a = make_float4(0.f, 0.f, 0.f, 0.f);
      #pragma unroll
      for (int m = 0; m < 4; ++m) {
        float4 w = wo[m], hv = h_lds[l + 64 * m];
        a.x = fmaf(w.x, hv.x, a.x); a.y = fmaf(w.y, hv.y, a.y);
        a.z = fmaf(w.z, hv.z, a.z); a.w = fmaf(w.w, hv.w, a.w);
      }
      float lv = (a.x + a.y) + (a.z + a.w);
      #pragma unroll
      for (int m = 1; m < 64; m <<= 1) lv += __shfl_xor(lv, m);
      if (l == 0) {
        float lt = lv + bias_o;
        lg_e[wv] = expf(lt);
        lg_b[wv] = ((vis >> wv) & 1u) ? -FLT_MAX : lt;
      }
    } else if (tid < 4) {
      lg_e[tid] = 0.f; lg_b[tid] = -FLT_MAX;
    }

    // ---- Phase A: my 4 gate-rows -> h_k[hrow] ----
    if (k < SEQ) {
      float4 a = make_float4(0.f, 0.f, 0.f, 0.f);
      a.x = fmaf(wi[0].x, xv0.x, a.x); a.y = fmaf(wi[0].y, xv0.y, a.y);
      a.z = fmaf(wi[0].z, xv0.z, a.z); a.w = fmaf(wi[0].w, xv0.w, a.w);
      a.x = fmaf(wi[1].x, xv1.x, a.x); a.y = fmaf(wi[1].y, xv1.y, a.y);
      a.z = fmaf(wi[1].z, xv1.z, a.z); a.w = fmaf(wi[1].w, xv1.w, a.w);
      a.x = fmaf(wi[2].x, xv2.x, a.x); a.y = fmaf(wi[2].y, xv2.y, a.y);
      a.z = fmaf(wi[2].z, xv2.z, a.z); a.w = fmaf(wi[2].w, xv2.w, a.w);
      a.x = fmaf(wi[3].x, xv3.x, a.x); a.y = fmaf(wi[3].y, xv3.y, a.y);
      a.z = fmaf(wi[3].z, xv3.z, a.z); a.w = fmaf(wi[3].w, xv3.w, a.w);
      #pragma unroll
      for (int m = 0; m < 16; ++m) {
        float4 w = wh[m], hv = h_lds[j + 16 * m];
        a.x = fmaf(w.x, hv.x, a.x); a.y = fmaf(w.y, hv.y, a.y);
        a.z = fmaf(w.z, hv.z, a.z); a.w = fmaf(w.w, hv.w, a.w);
      }
      float v = (a.x + a.y) + (a.z + a.w);
      v += __shfl_xor(v, 1); v += __shfl_xor(v, 2);
      v += __shfl_xor(v, 4); v += __shfl_xor(v, 8);
      v += bias_g;                       // same bias across the 16-lane group
      float gi = __shfl(v, 0),  gf = __shfl(v, 16);
      float gg = __shfl(v, 32), go = __shfl(v, 48);
      if (l == 0) {
        float ig = 1.f / (1.f + expf(-gi));
        float fg = 1.f / (1.f + expf(-gf));
        float g2 = tanhf(gg);
        float og = 1.f / (1.f + expf(-go));
        float cc = fmaf(fg, c0, ig * g2);   // quirk: c0 re-used every step
        h_new[wv] = og * tanhf(cc);
      }
    }
    __syncthreads();

    // ---- publish my mailbox (tid 0) ----
    if (tid == 0) {
      float s  = lg_e[0] + lg_e[1] + lg_e[2] + lg_e[3];
      float bv = lg_b[0]; int bi = b * 4;
      if (lg_b[1] > bv) { bv = lg_b[1]; bi = b * 4 + 1; }
      if (lg_b[2] > bv) { bv = lg_b[2]; bi = b * 4 + 2; }
      if (lg_b[3] > bv) { bv = lg_b[3]; bi = b * 4 + 3; }
      Mbox* mp = &mb[(k & 1) * NB + b];
      u64 d0 = pack_ff(h_new[0], h_new[1]);
      u64 d1 = pack_ff(h_new[2], h_new[3]);
      u64 d2 = pack_ff(s, bv);
      u64 d3 = (u64)(u32)bi | ((u64)(u32)(k + 1) << 32);
      __hip_atomic_store(&mp->q[0], d0, __ATOMIC_RELAXED, AGENT);
      __hip_atomic_store(&mp->q[1], d1, __ATOMIC_RELAXED, AGENT);
      __hip_atomic_store(&mp->q[2], d2, __ATOMIC_RELAXED, AGENT);
      __hip_atomic_store(&mp->q[3], d3, __ATOMIC_RELEASE, AGENT);
    }

    // ---- gather: thread i polls mailbox i ----
    Mbox* gp = &mb[(k & 1) * NB + tid];
    u64 d3 = __hip_atomic_load(&gp->q[3], __ATOMIC_ACQUIRE, AGENT);
    while ((u32)(d3 >> 32) != (u32)(k + 1)) {
      __builtin_amdgcn_s_sleep(1);
      d3 = __hip_atomic_load(&gp->q[3], __ATOMIC_ACQUIRE, AGENT);
    }
    u64 d0 = __hip_atomic_load(&gp->q[0], __ATOMIC_RELAXED, AGENT);
    u64 d1 = __hip_atomic_load(&gp->q[1], __ATOMIC_RELAXED, AGENT);
    u64 d2 = __hip_atomic_load(&gp->q[2], __ATOMIC_RELAXED, AGENT);
    if (k < SEQ) h_lds[tid] = make_float4(lo_f(d0), hi_f(d0), lo_f(d1), hi_f(d1));

    // ---- all-block-redundant finalize of step k-1 ----
    if (k >= 1) {
      float s_p = lo_f(d2), b_p = hi_f(d2);
      int   i_p = (int)(u32)d3;
      #pragma unroll
      for (int m = 1; m < 64; m <<= 1) {
        float s2 = __shfl_xor(s_p, m);
        float b2 = __shfl_xor(b_p, m);
        int   i2 = __shfl_xor(i_p, m);
        s_p += s2;
        if (b2 > b_p || (b2 == b_p && i2 < i_p)) { b_p = b2; i_p = i2; }
      }
      if (l == 0) { cw_s[wv] = s_p; cw_b[wv] = b_p; cw_i[wv] = i_p; }
      __syncthreads();
      if (tid == 0) {
        float s = cw_s[0], bv = cw_b[0]; int bi = cw_i[0];
        #pragma unroll
        for (int q = 1; q < 4; ++q) {
          s += cw_s[q];
          if (cw_b[q] > bv || (cw_b[q] == bv && cw_i[q] < bi)) { bv = cw_b[q]; bi = cw_i[q]; }
        }
        if ((bi >> 2) == b) vis |= 1u << (bi & 3);   // my row got picked
        if (b == 0) {
          out[k - 1]       = (float)bi;
          out[SEQ + k - 1] = bv - logf(s);
        }
      }
    }
    __syncthreads();   // h_lds complete + vis visible for next iteration
  }
}

extern "C" void kernel_launch(void* const* d_in, const int* in_sizes, int n_in,
                              void* d_out, int out_size, void* d_ws, size_t ws_size,
                              hipStream_t stream) {
  const float* X     = (const float*)d_in[0];
  const float* ENC   = (const float*)d_in[1];
  const float* W_ih  = (const float*)d_in[2];
  const float* W_hh  = (const float*)d_in[3];
  const float* b_ih  = (const float*)d_in[4];
  const float* b_hh  = (const float*)d_in[5];
  const float* W_out = (const float*)d_in[6];
  const float* b_out = (const float*)d_in[7];
  float* out = (float*)d_out;
  Mbox* mb = (Mbox*)d_ws;   // 2*NB*32 B = 16 KB

  decoder_main<<<NB, TPB, 0, stream>>>(X, ENC, W_ih, W_hh, b_ih, b_hh,
                                       W_out, b_out, out, mb);
}

// Round 3
// 10417.153 us; speedup vs baseline: 2.6840x; 2.6840x over previous
//
#include <hip/hip_runtime.h>
#include <math.h>
#include <float.h>

// Pointer-network decoder, 1024 sequential steps.
// R3: mailbox all-to-all exchange, zero atomic-RMW, RELAXED-only polling
// (agent-acquire emits cache invalidates on gfx950 -> R2's 65k acquire
// spinners thrashed L1/L2 and re-fetched weights 9x from HBM).
// __launch_bounds__(256,1) so the 96 weight floats/thread truly live in
// VGPRs (R2's (256,2) capped at 128 VGPRs -> compiler reloaded weights
// every step).

#define SEQ   1024
#define FEAT  256
#define HID   1024
#define NB    256
#define TPB   256
#define AGENT __HIP_MEMORY_SCOPE_AGENT

typedef unsigned long long u64;
typedef unsigned int       u32;

struct alignas(32) Mbox {          // one 32-B line per block per parity
  u64 q[4];  // q0=(h0,h1) q1=(h2,h3) q2=(esum,best) q3=(idx | tag<<32)
};

__device__ __forceinline__ u64 pack_ff(float a, float b) {
  return (u64)__float_as_uint(a) | ((u64)__float_as_uint(b) << 32);
}
__device__ __forceinline__ float lo_f(u64 d) { return __uint_as_float((u32)d); }
__device__ __forceinline__ float hi_f(u64 d) { return __uint_as_float((u32)(d >> 32)); }

extern "C" __global__ void __launch_bounds__(TPB, 1)
decoder_main(const float* __restrict__ X,      // (SEQ, FEAT)
             const float* __restrict__ ENC,    // (SEQ, HID)
             const float* __restrict__ W_ih,   // (4H, FEAT)
             const float* __restrict__ W_hh,   // (4H, HID)
             const float* __restrict__ b_ih,
             const float* __restrict__ b_hh,
             const float* __restrict__ W_out,  // (OUT, HID)
             const float* __restrict__ b_out,
             float* __restrict__ out,          // [idx(1024) | logp(1024)] as f32
             Mbox* __restrict__ mb)            // [2][NB]
{
  const int b   = blockIdx.x;
  const int tid = threadIdx.x;
  const int wv  = tid >> 6;          // wave 0..3  == local h/logit row
  const int r   = tid >> 4;          // gate-row 0..15 (phase A)
  const int j   = tid & 15;          // phase-A lane within row
  const int l   = tid & 63;          // phase-B lane within wave
  const int gate = r & 3;            // i,f,g,o
  const int hrow = b * 4 + (r >> 2); // phase-A h row
  const int grow = gate * HID + hrow;
  const int orow = b * 4 + wv;       // phase-B logit row

  __shared__ float4 h_lds[HID / 4];  // current h (4 KB)
  __shared__ float  h_new[4];
  __shared__ float  lg_e[4], lg_b[4];
  __shared__ float  cw_s[4], cw_b[4];
  __shared__ int    cw_i[4];
  __shared__ u32    vis;             // visited bits for this block's 4 rows

  // ---- one-time: weights into registers (96 floats/thread) ----
  const float4* WHH  = (const float4*)W_hh;
  const float4* WIH  = (const float4*)W_ih;
  const float4* WOUT = (const float4*)W_out;
  const float4* X4   = (const float4*)X;
  float4 wh[16], wi[4], wo[4];
  #pragma unroll
  for (int m = 0; m < 16; ++m) wh[m] = WHH[(size_t)grow * 256 + j + 16 * m];
  #pragma unroll
  for (int m = 0; m < 4; ++m)  wi[m] = WIH[(size_t)grow * 64 + j + 16 * m];
  #pragma unroll
  for (int m = 0; m < 4; ++m)  wo[m] = WOUT[(size_t)orow * 256 + l + 64 * m];
  const float bias_g = b_ih[grow] + b_hh[grow];
  const float bias_o = b_out[orow];
  const float c0     = ENC[(size_t)(SEQ - 1) * HID + hrow]; // quirk: c0 every step

  for (int i = tid; i < HID / 4; i += TPB) h_lds[i] = make_float4(0.f, 0.f, 0.f, 0.f);
  if (tid == 0) vis = 0u;
  __syncthreads();

  for (int k = 0; k <= SEQ; ++k) {
    // prefetch x_k slice (hides under phase B)
    float4 xv0, xv1, xv2, xv3;
    if (k < SEQ) {
      const float4* xr = X4 + (size_t)k * 64;
      xv0 = xr[j]; xv1 = xr[j + 16]; xv2 = xr[j + 32]; xv3 = xr[j + 48];
    }

    // ---- Phase B: partials of logits(k-1) from h_{k-1} in LDS ----
    if (k > 0) {
      float4 a = make_float4(0.f, 0.f, 0.f, 0.f);
      #pragma unroll
      for (int m = 0; m < 4; ++m) {
        float4 w = wo[m], hv = h_lds[l + 64 * m];
        a.x = fmaf(w.x, hv.x, a.x); a.y = fmaf(w.y, hv.y, a.y);
        a.z = fmaf(w.z, hv.z, a.z); a.w = fmaf(w.w, hv.w, a.w);
      }
      float lv = (a.x + a.y) + (a.z + a.w);
      #pragma unroll
      for (int m = 1; m < 64; m <<= 1) lv += __shfl_xor(lv, m);
      if (l == 0) {
        float lt = lv + bias_o;
        lg_e[wv] = expf(lt);
        lg_b[wv] = ((vis >> wv) & 1u) ? -FLT_MAX : lt;
      }
    } else if (tid < 4) {
      lg_e[tid] = 0.f; lg_b[tid] = -FLT_MAX;
    }

    // ---- Phase A: my gate-row -> h_k[hrow] ----
    if (k < SEQ) {
      float4 a = make_float4(0.f, 0.f, 0.f, 0.f);
      a.x = fmaf(wi[0].x, xv0.x, a.x); a.y = fmaf(wi[0].y, xv0.y, a.y);
      a.z = fmaf(wi[0].z, xv0.z, a.z); a.w = fmaf(wi[0].w, xv0.w, a.w);
      a.x = fmaf(wi[1].x, xv1.x, a.x); a.y = fmaf(wi[1].y, xv1.y, a.y);
      a.z = fmaf(wi[1].z, xv1.z, a.z); a.w = fmaf(wi[1].w, xv1.w, a.w);
      a.x = fmaf(wi[2].x, xv2.x, a.x); a.y = fmaf(wi[2].y, xv2.y, a.y);
      a.z = fmaf(wi[2].z, xv2.z, a.z); a.w = fmaf(wi[2].w, xv2.w, a.w);
      a.x = fmaf(wi[3].x, xv3.x, a.x); a.y = fmaf(wi[3].y, xv3.y, a.y);
      a.z = fmaf(wi[3].z, xv3.z, a.z); a.w = fmaf(wi[3].w, xv3.w, a.w);
      #pragma unroll
      for (int m = 0; m < 16; ++m) {
        float4 w = wh[m], hv = h_lds[j + 16 * m];
        a.x = fmaf(w.x, hv.x, a.x); a.y = fmaf(w.y, hv.y, a.y);
        a.z = fmaf(w.z, hv.z, a.z); a.w = fmaf(w.w, hv.w, a.w);
      }
      float v = (a.x + a.y) + (a.z + a.w);
      v += __shfl_xor(v, 1); v += __shfl_xor(v, 2);
      v += __shfl_xor(v, 4); v += __shfl_xor(v, 8);
      v += bias_g;
      float gi = __shfl(v, 0),  gf = __shfl(v, 16);
      float gg = __shfl(v, 32), go = __shfl(v, 48);
      if (l == 0) {
        float ig = 1.f / (1.f + expf(-gi));
        float fg = 1.f / (1.f + expf(-gf));
        float g2 = tanhf(gg);
        float og = 1.f / (1.f + expf(-go));
        float cc = fmaf(fg, c0, ig * g2);   // quirk: c0 re-used every step
        h_new[wv] = og * tanhf(cc);
      }
    }
    __syncthreads();

    // ---- publish my mailbox (tid 0): relaxed data + release tag ----
    if (tid == 0) {
      float s  = lg_e[0] + lg_e[1] + lg_e[2] + lg_e[3];
      float bv = lg_b[0]; int bi = b * 4;
      if (lg_b[1] > bv) { bv = lg_b[1]; bi = b * 4 + 1; }
      if (lg_b[2] > bv) { bv = lg_b[2]; bi = b * 4 + 2; }
      if (lg_b[3] > bv) { bv = lg_b[3]; bi = b * 4 + 3; }
      Mbox* mp = &mb[(k & 1) * NB + b];
      __hip_atomic_store(&mp->q[0], pack_ff(h_new[0], h_new[1]), __ATOMIC_RELAXED, AGENT);
      __hip_atomic_store(&mp->q[1], pack_ff(h_new[2], h_new[3]), __ATOMIC_RELAXED, AGENT);
      __hip_atomic_store(&mp->q[2], pack_ff(s, bv),              __ATOMIC_RELAXED, AGENT);
      u64 d3 = (u64)(u32)bi | ((u64)(u32)(k + 1) << 32);
      __hip_atomic_store(&mp->q[3], d3, __ATOMIC_RELEASE, AGENT);
    }

    // ---- gather: thread i polls mailbox i (RELAXED spin, no invalidates) ----
    Mbox* gp = &mb[(k & 1) * NB + tid];
    u64 d3 = __hip_atomic_load(&gp->q[3], __ATOMIC_RELAXED, AGENT);
    while ((u32)(d3 >> 32) != (u32)(k + 1)) {
      __builtin_amdgcn_s_sleep(4);
      d3 = __hip_atomic_load(&gp->q[3], __ATOMIC_RELAXED, AGENT);
    }
    __builtin_amdgcn_sched_barrier(0);   // data loads must issue after tag check
    u64 d0 = __hip_atomic_load(&gp->q[0], __ATOMIC_RELAXED, AGENT);
    u64 d1 = __hip_atomic_load(&gp->q[1], __ATOMIC_RELAXED, AGENT);
    u64 d2 = __hip_atomic_load(&gp->q[2], __ATOMIC_RELAXED, AGENT);
    if (k < SEQ) h_lds[tid] = make_float4(lo_f(d0), hi_f(d0), lo_f(d1), hi_f(d1));

    // ---- all-block-redundant finalize of step k-1 ----
    if (k >= 1) {
      float s_p = lo_f(d2), b_p = hi_f(d2);
      int   i_p = (int)(u32)d3;
      #pragma unroll
      for (int m = 1; m < 64; m <<= 1) {
        float s2 = __shfl_xor(s_p, m);
        float b2 = __shfl_xor(b_p, m);
        int   i2 = __shfl_xor(i_p, m);
        s_p += s2;
        if (b2 > b_p || (b2 == b_p && i2 < i_p)) { b_p = b2; i_p = i2; }
      }
      if (l == 0) { cw_s[wv] = s_p; cw_b[wv] = b_p; cw_i[wv] = i_p; }
      __syncthreads();
      if (tid == 0) {
        float s = cw_s[0], bv = cw_b[0]; int bi = cw_i[0];
        #pragma unroll
        for (int q = 1; q < 4; ++q) {
          s += cw_s[q];
          if (cw_b[q] > bv || (cw_b[q] == bv && cw_i[q] < bi)) { bv = cw_b[q]; bi = cw_i[q]; }
        }
        if ((bi >> 2) == b) vis |= 1u << (bi & 3);   // my row got picked
        if (b == 0) {
          out[k - 1]       = (float)bi;
          out[SEQ + k - 1] = bv - logf(s);
        }
      }
    }
    __syncthreads();   // h_lds + vis coherent for next iteration
  }
}

extern "C" void kernel_launch(void* const* d_in, const int* in_sizes, int n_in,
                              void* d_out, int out_size, void* d_ws, size_t ws_size,
                              hipStream_t stream) {
  const float* X     = (const float*)d_in[0];
  const float* ENC   = (const float*)d_in[1];
  const float* W_ih  = (const float*)d_in[2];
  const float* W_hh  = (const float*)d_in[3];
  const float* b_ih  = (const float*)d_in[4];
  const float* b_hh  = (const float*)d_in[5];
  const float* W_out = (const float*)d_in[6];
  const float* b_out = (const float*)d_in[7];
  float* out = (float*)d_out;
  Mbox* mb = (Mbox*)d_ws;   // 2*NB*32 B = 16 KB

  decoder_main<<<NB, TPB, 0, stream>>>(X, ENC, W_ih, W_hh, b_ih, b_hh,
                                       W_out, b_out, out, mb);
}

// Round 4
// 6789.877 us; speedup vs baseline: 4.1178x; 1.5342x over previous
//
#include <hip/hip_runtime.h>
#include <math.h>
#include <float.h>

// Pointer-network decoder, 1024 sequential steps.
// R4: (a) weights staged in LDS (100 KB/block) -> zero steady-state weight
// traffic, no L2 capacity thrash (R3 showed compiler won't keep them in
// VGPRs and L2 slightly over capacity); (b) hierarchical sync: block 0
// aggregates all 256 mailboxes and publishes ONE flag; workers poll that
// flag with ONE thread each -> poll fabric demand drops ~40x (R3 was
// coherence-fabric-congestion-bound: 65k pollers saturated the MALL).

#define SEQ   1024
#define FEAT  256
#define HID   1024
#define ONUM  1024
#define NB    256
#define TPB   256
#define AGENT __HIP_MEMORY_SCOPE_AGENT

typedef unsigned long long u64;
typedef unsigned int       u32;

struct alignas(32) Mbox {          // one 32-B line per block per parity
  u64 q[4];  // q0=(h0,h1) q1=(h2,h3) q2=(esum,best) q3=(idx | tag<<32)
};

__device__ __forceinline__ u64 pack_ff(float a, float b) {
  return (u64)__float_as_uint(a) | ((u64)__float_as_uint(b) << 32);
}
__device__ __forceinline__ float lo_f(u64 d) { return __uint_as_float((u32)d); }
__device__ __forceinline__ float hi_f(u64 d) { return __uint_as_float((u32)(d >> 32)); }

// WHC: number of 16-float4 wh chunks staged in LDS (16 = all).
// SIO: stage wi/wo in LDS too.
template<int WHC, bool SIO>
__global__ void __launch_bounds__(TPB, 1)
decoder_main(const float* __restrict__ X,      // (SEQ, FEAT)
             const float* __restrict__ ENC,    // (SEQ, HID)
             const float* __restrict__ W_ih,   // (4H, FEAT)
             const float* __restrict__ W_hh,   // (4H, HID)
             const float* __restrict__ b_ih,
             const float* __restrict__ b_hh,
             const float* __restrict__ W_out,  // (OUT, HID)
             const float* __restrict__ b_out,
             float* __restrict__ out,          // [idx(1024) | logp(1024)] f32
             Mbox* __restrict__ mb,            // [2][NB]
             u64* __restrict__ flag)           // [2]
{
  const int b   = blockIdx.x;
  const int tid = threadIdx.x;
  const int wv  = tid >> 6;          // wave 0..3  == local h/logit row
  const int j   = tid & 15;          // phase-A lane within gate-row
  const int l   = tid & 63;          // lane within wave
  const int gate = l >> 4;           // i,f,g,o (16 lanes each)
  const int hrow = b * 4 + wv;       // this wave's h row
  const int grow = gate * HID + hrow;
  const int orow = b * 4 + wv;       // phase-B logit row

  extern __shared__ float4 lds[];
  float4* whL = lds;                                   // WHC*256 float4
  float4* wiL = lds + WHC * 256;                       // SIO: 1024
  float4* woL = lds + WHC * 256 + (SIO ? 1024 : 0);    // SIO: 1024
  float4* hL  = lds + WHC * 256 + (SIO ? 2048 : 0);    // 256 float4 = h

  __shared__ float h_new[4];
  __shared__ float lg_e[4], lg_b[4];
  __shared__ float cw_s[4], cw_b[4];
  __shared__ int   cw_i[4];
  __shared__ u32   vis;

  const float4* WHH  = (const float4*)W_hh;
  const float4* WIH  = (const float4*)W_ih;
  const float4* WOUT = (const float4*)W_out;
  const float4* X4   = (const float4*)X;

  // ---- one-time staging ----
  #pragma unroll
  for (int m = 0; m < WHC; ++m)
    whL[m * 256 + tid] = WHH[(size_t)grow * 256 + j + 16 * m];
  float4 whr[(WHC < 16) ? (16 - WHC) : 1];
  if constexpr (WHC < 16) {
    #pragma unroll
    for (int m = WHC; m < 16; ++m)
      whr[m - WHC] = WHH[(size_t)grow * 256 + j + 16 * m];
  }
  float4 wir[SIO ? 1 : 4], wor[SIO ? 1 : 4];
  if constexpr (SIO) {
    #pragma unroll
    for (int m = 0; m < 4; ++m)
      wiL[m * 256 + tid] = WIH[(size_t)grow * 64 + j + 16 * m];
    #pragma unroll
    for (int m = 0; m < 4; ++m)
      woL[m * 256 + tid] = WOUT[(size_t)orow * 256 + l + 64 * m];
  } else {
    #pragma unroll
    for (int m = 0; m < 4; ++m)
      wir[m] = WIH[(size_t)grow * 64 + j + 16 * m];
    #pragma unroll
    for (int m = 0; m < 4; ++m)
      wor[m] = WOUT[(size_t)orow * 256 + l + 64 * m];
  }
  const float bias_g = b_ih[grow] + b_hh[grow];
  const float bias_o = b_out[orow];
  const float c0     = ENC[(size_t)(SEQ - 1) * HID + hrow]; // quirk: c0 every step

  hL[tid] = make_float4(0.f, 0.f, 0.f, 0.f);
  if (tid == 0) vis = 0u;
  __syncthreads();

  for (int k = 0; k <= SEQ; ++k) {
    const int par = k & 1;

    float4 xv0, xv1, xv2, xv3;
    if (k < SEQ) {
      const float4* xr = X4 + (size_t)k * 64;
      xv0 = xr[j]; xv1 = xr[j + 16]; xv2 = xr[j + 32]; xv3 = xr[j + 48];
    }

    // ---- Phase B: logits(k-1) partials from h_{k-1} ----
    if (k > 0) {
      float4 a0 = make_float4(0.f, 0.f, 0.f, 0.f);
      float4 a1 = make_float4(0.f, 0.f, 0.f, 0.f);
      #pragma unroll
      for (int m = 0; m < 4; m += 2) {
        float4 w0 = SIO ? woL[m * 256 + tid] : wor[m];
        float4 h0 = hL[l + 64 * m];
        float4 w1 = SIO ? woL[(m + 1) * 256 + tid] : wor[m + 1];
        float4 h1 = hL[l + 64 * (m + 1)];
        a0.x = fmaf(w0.x, h0.x, a0.x); a0.y = fmaf(w0.y, h0.y, a0.y);
        a0.z = fmaf(w0.z, h0.z, a0.z); a0.w = fmaf(w0.w, h0.w, a0.w);
        a1.x = fmaf(w1.x, h1.x, a1.x); a1.y = fmaf(w1.y, h1.y, a1.y);
        a1.z = fmaf(w1.z, h1.z, a1.z); a1.w = fmaf(w1.w, h1.w, a1.w);
      }
      float lv = ((a0.x + a0.y) + (a0.z + a0.w)) + ((a1.x + a1.y) + (a1.z + a1.w));
      #pragma unroll
      for (int m = 1; m < 64; m <<= 1) lv += __shfl_xor(lv, m);
      if (l == 0) {
        float lt = lv + bias_o;
        lg_e[wv] = expf(lt);
        lg_b[wv] = ((vis >> wv) & 1u) ? -FLT_MAX : lt;
      }
    } else if (tid < 4) {
      lg_e[tid] = 0.f; lg_b[tid] = -FLT_MAX;
    }

    // ---- Phase A: gate dot-products -> h_k ----
    if (k < SEQ) {
      float4 a0 = make_float4(0.f, 0.f, 0.f, 0.f);
      float4 a1 = make_float4(0.f, 0.f, 0.f, 0.f);
      {
        float4 w0 = SIO ? wiL[0 * 256 + tid] : wir[0];
        float4 w1 = SIO ? wiL[1 * 256 + tid] : wir[1];
        float4 w2 = SIO ? wiL[2 * 256 + tid] : wir[2];
        float4 w3 = SIO ? wiL[3 * 256 + tid] : wir[3];
        a0.x = fmaf(w0.x, xv0.x, a0.x); a0.y = fmaf(w0.y, xv0.y, a0.y);
        a0.z = fmaf(w0.z, xv0.z, a0.z); a0.w = fmaf(w0.w, xv0.w, a0.w);
        a1.x = fmaf(w1.x, xv1.x, a1.x); a1.y = fmaf(w1.y, xv1.y, a1.y);
        a1.z = fmaf(w1.z, xv1.z, a1.z); a1.w = fmaf(w1.w, xv1.w, a1.w);
        a0.x = fmaf(w2.x, xv2.x, a0.x); a0.y = fmaf(w2.y, xv2.y, a0.y);
        a0.z = fmaf(w2.z, xv2.z, a0.z); a0.w = fmaf(w2.w, xv2.w, a0.w);
        a1.x = fmaf(w3.x, xv3.x, a1.x); a1.y = fmaf(w3.y, xv3.y, a1.y);
        a1.z = fmaf(w3.z, xv3.z, a1.z); a1.w = fmaf(w3.w, xv3.w, a1.w);
      }
      #pragma unroll
      for (int m = 0; m < 16; m += 2) {
        float4 w0 = (m < WHC) ? whL[m * 256 + tid] : whr[(m >= WHC) ? (m - WHC) : 0];
        float4 h0 = hL[j + 16 * m];
        float4 w1 = ((m + 1) < WHC) ? whL[(m + 1) * 256 + tid] : whr[((m + 1) >= WHC) ? (m + 1 - WHC) : 0];
        float4 h1 = hL[j + 16 * (m + 1)];
        a0.x = fmaf(w0.x, h0.x, a0.x); a0.y = fmaf(w0.y, h0.y, a0.y);
        a0.z = fmaf(w0.z, h0.z, a0.z); a0.w = fmaf(w0.w, h0.w, a0.w);
        a1.x = fmaf(w1.x, h1.x, a1.x); a1.y = fmaf(w1.y, h1.y, a1.y);
        a1.z = fmaf(w1.z, h1.z, a1.z); a1.w = fmaf(w1.w, h1.w, a1.w);
      }
      float v = ((a0.x + a0.y) + (a0.z + a0.w)) + ((a1.x + a1.y) + (a1.z + a1.w));
      v += __shfl_xor(v, 1); v += __shfl_xor(v, 2);
      v += __shfl_xor(v, 4); v += __shfl_xor(v, 8);
      v += bias_g;
      float gi = __shfl(v, wv * 64 + 0),  gf = __shfl(v, wv * 64 + 16);
      float gg = __shfl(v, wv * 64 + 32), go = __shfl(v, wv * 64 + 48);
      if (l == 0) {
        float ig = 1.f / (1.f + expf(-gi));
        float fg = 1.f / (1.f + expf(-gf));
        float g2 = tanhf(gg);
        float og = 1.f / (1.f + expf(-go));
        float cc = fmaf(fg, c0, ig * g2);
        h_new[wv] = og * tanhf(cc);
      }
    }
    __syncthreads();   // h_new/lg ready; hL free to overwrite

    // ---- publish mailbox (tid 0) ----
    if (tid == 0) {
      float s  = lg_e[0] + lg_e[1] + lg_e[2] + lg_e[3];
      float bv = lg_b[0]; int bi = b * 4;
      if (lg_b[1] > bv) { bv = lg_b[1]; bi = b * 4 + 1; }
      if (lg_b[2] > bv) { bv = lg_b[2]; bi = b * 4 + 2; }
      if (lg_b[3] > bv) { bv = lg_b[3]; bi = b * 4 + 3; }
      Mbox* mp = &mb[par * NB + b];
      __hip_atomic_store(&mp->q[0], pack_ff(h_new[0], h_new[1]), __ATOMIC_RELAXED, AGENT);
      __hip_atomic_store(&mp->q[1], pack_ff(h_new[2], h_new[3]), __ATOMIC_RELAXED, AGENT);
      __hip_atomic_store(&mp->q[2], pack_ff(s, bv),              __ATOMIC_RELAXED, AGENT);
      u64 d3 = (u64)(u32)bi | ((u64)(u32)(k + 1) << 32);
      __hip_atomic_store(&mp->q[3], d3, __ATOMIC_RELEASE, AGENT);
    }

    if (b == 0) {
      // ===== aggregator: poll all 256 tags, reduce, flag =====
      Mbox* gp = &mb[par * NB + tid];
      u64 d3 = __hip_atomic_load(&gp->q[3], __ATOMIC_RELAXED, AGENT);
      while ((u32)(d3 >> 32) != (u32)(k + 1)) {
        __builtin_amdgcn_s_sleep(1);
        d3 = __hip_atomic_load(&gp->q[3], __ATOMIC_RELAXED, AGENT);
      }
      __builtin_amdgcn_sched_barrier(0);
      u64 d2 = __hip_atomic_load(&gp->q[2], __ATOMIC_RELAXED, AGENT);
      if (k < SEQ) {
        u64 d0 = __hip_atomic_load(&gp->q[0], __ATOMIC_RELAXED, AGENT);
        u64 d1 = __hip_atomic_load(&gp->q[1], __ATOMIC_RELAXED, AGENT);
        hL[tid] = make_float4(lo_f(d0), hi_f(d0), lo_f(d1), hi_f(d1));
      }
      float s_p = lo_f(d2), b_p = hi_f(d2);
      int   i_p = (int)(u32)d3;
      #pragma unroll
      for (int m = 1; m < 64; m <<= 1) {
        float s2 = __shfl_xor(s_p, m);
        float b2 = __shfl_xor(b_p, m);
        int   i2 = __shfl_xor(i_p, m);
        s_p += s2;
        if (b2 > b_p || (b2 == b_p && i2 < i_p)) { b_p = b2; i_p = i2; }
      }
      if (l == 0) { cw_s[wv] = s_p; cw_b[wv] = b_p; cw_i[wv] = i_p; }
      __syncthreads();
      if (tid == 0) {
        float s = cw_s[0], bv = cw_b[0]; int bi = cw_i[0];
        #pragma unroll
        for (int q = 1; q < 4; ++q) {
          s += cw_s[q];
          if (cw_b[q] > bv || (cw_b[q] == bv && cw_i[q] < bi)) { bv = cw_b[q]; bi = cw_i[q]; }
        }
        if (k >= 1) {
          out[k - 1]       = (float)bi;
          out[SEQ + k - 1] = bv - logf(s);
          if ((bi >> 2) == b) vis |= 1u << (bi & 3);
        }
        if (k < SEQ) {
          u64 f = (u64)(u32)bi | ((u64)(u32)(k + 1) << 32);
          __hip_atomic_store(&flag[par], f, __ATOMIC_RELEASE, AGENT);
        }
      }
    } else {
      // ===== worker: one-thread flag poll, one-shot h gather =====
      if (k == SEQ) break;   // block-uniform; nothing left to do
      if (tid == 0) {
        u64 f = __hip_atomic_load(&flag[par], __ATOMIC_RELAXED, AGENT);
        while ((u32)(f >> 32) != (u32)(k + 1)) {
          __builtin_amdgcn_s_sleep(2);
          f = __hip_atomic_load(&flag[par], __ATOMIC_RELAXED, AGENT);
        }
        int bi = (int)(u32)f;
        if (k >= 1 && (bi >> 2) == b) vis |= 1u << (bi & 3);
      }
      __syncthreads();                      // flag observed by all
      __builtin_amdgcn_sched_barrier(0);
      Mbox* gp = &mb[par * NB + tid];
      u64 d0 = __hip_atomic_load(&gp->q[0], __ATOMIC_RELAXED, AGENT);
      u64 d1 = __hip_atomic_load(&gp->q[1], __ATOMIC_RELAXED, AGENT);
      hL[tid] = make_float4(lo_f(d0), hi_f(d0), lo_f(d1), hi_f(d1));
    }
    __syncthreads();   // hL complete; vis updated
  }
}

extern "C" void kernel_launch(void* const* d_in, const int* in_sizes, int n_in,
                              void* d_out, int out_size, void* d_ws, size_t ws_size,
                              hipStream_t stream) {
  const float* X     = (const float*)d_in[0];
  const float* ENC   = (const float*)d_in[1];
  const float* W_ih  = (const float*)d_in[2];
  const float* W_hh  = (const float*)d_in[3];
  const float* b_ih  = (const float*)d_in[4];
  const float* b_hh  = (const float*)d_in[5];
  const float* W_out = (const float*)d_in[6];
  const float* b_out = (const float*)d_in[7];
  float* out = (float*)d_out;
  Mbox* mb  = (Mbox*)d_ws;                         // 2*NB*32 = 16 KB
  u64* flag = (u64*)((char*)d_ws + 2 * NB * 32);   // 16 B

  const int big_bytes   = (16 * 256 + 1024 + 1024 + 256) * 16;  // 102400
  const int small_bytes = (14 * 256 + 256) * 16;                // 61440

  hipError_t e = hipFuncSetAttribute(
      reinterpret_cast<const void*>(&decoder_main<16, true>),
      hipFuncAttributeMaxDynamicSharedMemorySize, big_bytes);
  if (e == hipSuccess) {
    decoder_main<16, true><<<NB, TPB, big_bytes, stream>>>(
        X, ENC, W_ih, W_hh, b_ih, b_hh, W_out, b_out, out, mb, flag);
  } else {
    decoder_main<14, false><<<NB, TPB, small_bytes, stream>>>(
        X, ENC, W_ih, W_hh, b_ih, b_hh, W_out, b_out, out, mb, flag);
  }
}

// Round 8
// 6693.941 us; speedup vs baseline: 4.1768x; 1.0143x over previous
//
#include <hip/hip_runtime.h>
#include <math.h>
#include <float.h>

// Pointer-network decoder, 1024 sequential steps.
// R8 == R7 with the Phase-A FMA transcription typo fixed (a1.z/a1.w).
// h broadcast via per-step FRESH global buffer (hist[k]) written with
// cache-bypass atomic stores and read with NORMAL CACHED loads -> per-XCD L2
// amplifies the broadcast (32 blocks share one MALL fill). Kills the 130k
// atomic-loads/step gather that bounded R4 (fabric atomic throughput ~16/cyc).
// Hierarchical signaling: agg (block 0) polls 256 tags, sets flagH (h ready)
// BEFORE reducing partials; pick rides in flagP consumed one step later
// (off critical path). Agent-scope acquire fence at kernel entry invalidates
// stale L1/L2 lines from the previous graph replay (hist values are
// deterministic across replays, so even a stale hit is value-identical).

#define SEQ   1024
#define FEAT  256
#define HID   1024
#define NB    256
#define TPB   256
#define AGENT __HIP_MEMORY_SCOPE_AGENT

typedef unsigned long long u64;
typedef unsigned int       u32;

struct alignas(32) Mbox { u64 q[4]; };  // q2=(esum,best) q3=(idx|tag<<32)

__device__ __forceinline__ u64 pack_ff(float a, float b) {
  return (u64)__float_as_uint(a) | ((u64)__float_as_uint(b) << 32);
}
__device__ __forceinline__ float lo_f(u64 d) { return __uint_as_float((u32)d); }
__device__ __forceinline__ float hi_f(u64 d) { return __uint_as_float((u32)(d >> 32)); }

extern "C" __global__ void __launch_bounds__(TPB, 1)
decoder_r5(const float* __restrict__ X,
           const float* __restrict__ ENC,
           const float* __restrict__ W_ih,
           const float* __restrict__ W_hh,
           const float* __restrict__ b_ih,
           const float* __restrict__ b_hh,
           const float* __restrict__ W_out,
           const float* __restrict__ b_out,
           float* __restrict__ out,
           float* __restrict__ hist,     // [SEQ][HID] fresh h per step
           Mbox* __restrict__ mb,        // [2][NB] partials
           u64* __restrict__ flagH,      // [2]
           u64* __restrict__ flagP)      // [2]
{
  const int b   = blockIdx.x;
  const int tid = threadIdx.x;
  const int wv  = tid >> 6;
  const int j   = tid & 15;
  const int l   = tid & 63;
  const int gate = l >> 4;
  const int hrow = b * 4 + wv;
  const int grow = gate * HID + hrow;
  const int orow = b * 4 + wv;

  // Invalidate stale L1/L2 lines left by the previous graph replay.
  __builtin_amdgcn_fence(__ATOMIC_ACQUIRE, "agent");
  __builtin_amdgcn_sched_barrier(0);

  extern __shared__ float4 lds[];
  float4* whL = lds;                    // 16*256
  float4* wiL = lds + 16 * 256;         // 1024
  float4* woL = lds + 16 * 256 + 1024;  // 1024
  float4* hL  = lds + 16 * 256 + 2048;  // 256

  __shared__ float h_new[4];
  __shared__ float lg_e[4], lg_b[4];
  __shared__ float cw_s[4], cw_b[4];
  __shared__ int   cw_i[4];
  __shared__ u32   vis;

  const float4* WHH  = (const float4*)W_hh;
  const float4* WIH  = (const float4*)W_ih;
  const float4* WOUT = (const float4*)W_out;
  const float4* X4   = (const float4*)X;
  const float4* hist4 = (const float4*)hist;
  u64* hist64 = (u64*)hist;

  #pragma unroll
  for (int m = 0; m < 16; ++m)
    whL[m * 256 + tid] = WHH[(size_t)grow * 256 + j + 16 * m];
  #pragma unroll
  for (int m = 0; m < 4; ++m)
    wiL[m * 256 + tid] = WIH[(size_t)grow * 64 + j + 16 * m];
  #pragma unroll
  for (int m = 0; m < 4; ++m)
    woL[m * 256 + tid] = WOUT[(size_t)orow * 256 + l + 64 * m];
  const float bias_g = b_ih[grow] + b_hh[grow];
  const float bias_o = b_out[orow];
  const float c0     = ENC[(size_t)(SEQ - 1) * HID + hrow];  // quirk: c0 every step

  hL[tid] = make_float4(0.f, 0.f, 0.f, 0.f);
  if (tid == 0) vis = 0u;
  __syncthreads();

  for (int k = 0; k <= SEQ; ++k) {
    const int par = k & 1;

    // ---- worker: consume pick(k-2) from flagP (off critical path) ----
    if (b != 0 && tid == 0 && k >= 2) {
      u64 f = __hip_atomic_load(&flagP[(k - 1) & 1], __ATOMIC_RELAXED, AGENT);
      while ((u32)(f >> 32) != (u32)k) {
        __builtin_amdgcn_s_sleep(1);
        f = __hip_atomic_load(&flagP[(k - 1) & 1], __ATOMIC_RELAXED, AGENT);
      }
      int bi = (int)(u32)f;
      if ((bi >> 2) == b) vis |= 1u << (bi & 3);
    }
    __syncthreads();   // vis + hL(gathered last iter) visible to phases

    float4 xv0, xv1, xv2, xv3;
    if (k < SEQ) {
      const float4* xr = X4 + (size_t)k * 64;
      xv0 = xr[j]; xv1 = xr[j + 16]; xv2 = xr[j + 32]; xv3 = xr[j + 48];
    }

    // ---- Phase B: logits(k-1) partials from h_{k-1} ----
    if (k > 0) {
      float4 a0 = make_float4(0.f, 0.f, 0.f, 0.f);
      float4 a1 = make_float4(0.f, 0.f, 0.f, 0.f);
      #pragma unroll
      for (int m = 0; m < 4; m += 2) {
        float4 w0 = woL[m * 256 + tid],       h0 = hL[l + 64 * m];
        float4 w1 = woL[(m + 1) * 256 + tid], h1 = hL[l + 64 * (m + 1)];
        a0.x = fmaf(w0.x, h0.x, a0.x); a0.y = fmaf(w0.y, h0.y, a0.y);
        a0.z = fmaf(w0.z, h0.z, a0.z); a0.w = fmaf(w0.w, h0.w, a0.w);
        a1.x = fmaf(w1.x, h1.x, a1.x); a1.y = fmaf(w1.y, h1.y, a1.y);
        a1.z = fmaf(w1.z, h1.z, a1.z); a1.w = fmaf(w1.w, h1.w, a1.w);
      }
      float lv = ((a0.x + a0.y) + (a0.z + a0.w)) + ((a1.x + a1.y) + (a1.z + a1.w));
      #pragma unroll
      for (int m = 1; m < 64; m <<= 1) lv += __shfl_xor(lv, m);
      if (l == 0) {
        float lt = lv + bias_o;
        lg_e[wv] = expf(lt);
        lg_b[wv] = ((vis >> wv) & 1u) ? -FLT_MAX : lt;
      }
    } else if (tid < 4) {
      lg_e[tid] = 0.f; lg_b[tid] = -FLT_MAX;
    }

    // ---- Phase A: h_k ----
    if (k < SEQ) {
      float4 a0 = make_float4(0.f, 0.f, 0.f, 0.f);
      float4 a1 = make_float4(0.f, 0.f, 0.f, 0.f);
      {
        float4 w0 = wiL[0 * 256 + tid], w1 = wiL[1 * 256 + tid];
        float4 w2 = wiL[2 * 256 + tid], w3 = wiL[3 * 256 + tid];
        a0.x = fmaf(w0.x, xv0.x, a0.x); a0.y = fmaf(w0.y, xv0.y, a0.y);
        a0.z = fmaf(w0.z, xv0.z, a0.z); a0.w = fmaf(w0.w, xv0.w, a0.w);
        a1.x = fmaf(w1.x, xv1.x, a1.x); a1.y = fmaf(w1.y, xv1.y, a1.y);
        a1.z = fmaf(w1.z, xv1.z, a1.z); a1.w = fmaf(w1.w, xv1.w, a1.w);
        a0.x = fmaf(w2.x, xv2.x, a0.x); a0.y = fmaf(w2.y, xv2.y, a0.y);
        a0.z = fmaf(w2.z, xv2.z, a0.z); a0.w = fmaf(w2.w, xv2.w, a0.w);
        a1.x = fmaf(w3.x, xv3.x, a1.x); a1.y = fmaf(w3.y, xv3.y, a1.y);
        a1.z = fmaf(w3.z, xv3.z, a1.z); a1.w = fmaf(w3.w, xv3.w, a1.w);
      }
      #pragma unroll
      for (int m = 0; m < 16; m += 2) {
        float4 w0 = whL[m * 256 + tid],       h0 = hL[j + 16 * m];
        float4 w1 = whL[(m + 1) * 256 + tid], h1 = hL[j + 16 * (m + 1)];
        a0.x = fmaf(w0.x, h0.x, a0.x); a0.y = fmaf(w0.y, h0.y, a0.y);
        a0.z = fmaf(w0.z, h0.z, a0.z); a0.w = fmaf(w0.w, h0.w, a0.w);
        a1.x = fmaf(w1.x, h1.x, a1.x); a1.y = fmaf(w1.y, h1.y, a1.y);
        a1.z = fmaf(w1.z, h1.z, a1.z); a1.w = fmaf(w1.w, h1.w, a1.w);
      }
      float v = ((a0.x + a0.y) + (a0.z + a0.w)) + ((a1.x + a1.y) + (a1.z + a1.w));
      v += __shfl_xor(v, 1); v += __shfl_xor(v, 2);
      v += __shfl_xor(v, 4); v += __shfl_xor(v, 8);
      v += bias_g;
      float gi = __shfl(v, wv * 64 + 0),  gf = __shfl(v, wv * 64 + 16);
      float gg = __shfl(v, wv * 64 + 32), go = __shfl(v, wv * 64 + 48);
      if (l == 0) {
        float ig = 1.f / (1.f + expf(-gi));
        float fg = 1.f / (1.f + expf(-gf));
        float g2 = tanhf(gg);
        float og = 1.f / (1.f + expf(-go));
        float cc = fmaf(fg, c0, ig * g2);
        h_new[wv] = og * tanhf(cc);
      }
    }
    __syncthreads();   // h_new/lg ready; hL reads done

    // ---- publish: hist (h_k) + partials mailbox ----
    if (tid == 0) {
      float s  = lg_e[0] + lg_e[1] + lg_e[2] + lg_e[3];
      float bv = lg_b[0]; int bi = b * 4;
      if (lg_b[1] > bv) { bv = lg_b[1]; bi = b * 4 + 1; }
      if (lg_b[2] > bv) { bv = lg_b[2]; bi = b * 4 + 2; }
      if (lg_b[3] > bv) { bv = lg_b[3]; bi = b * 4 + 3; }
      if (k < SEQ) {
        __hip_atomic_store(&hist64[(size_t)k * 512 + b * 2],
                           pack_ff(h_new[0], h_new[1]), __ATOMIC_RELAXED, AGENT);
        __hip_atomic_store(&hist64[(size_t)k * 512 + b * 2 + 1],
                           pack_ff(h_new[2], h_new[3]), __ATOMIC_RELAXED, AGENT);
      }
      Mbox* mp = &mb[par * NB + b];
      __hip_atomic_store(&mp->q[2], pack_ff(s, bv), __ATOMIC_RELAXED, AGENT);
      u64 d3 = (u64)(u32)bi | ((u64)(u32)(k + 1) << 32);
      __hip_atomic_store(&mp->q[3], d3, __ATOMIC_RELEASE, AGENT);
    }

    if (b == 0) {
      // ===== aggregator =====
      Mbox* gp = &mb[par * NB + tid];
      u64 d3 = __hip_atomic_load(&gp->q[3], __ATOMIC_RELAXED, AGENT);
      while ((u32)(d3 >> 32) != (u32)(k + 1)) {
        __builtin_amdgcn_s_sleep(1);
        d3 = __hip_atomic_load(&gp->q[3], __ATOMIC_RELAXED, AGENT);
      }
      __builtin_amdgcn_sched_barrier(0);
      u64 d2 = __hip_atomic_load(&gp->q[2], __ATOMIC_RELAXED, AGENT);
      __syncthreads();   // all 256 tags confirmed -> hist fully written
      if (tid == 0 && k < SEQ)
        __hip_atomic_store(&flagH[par], (u64)(u32)(k + 1), __ATOMIC_RELEASE, AGENT);
      // reduce partials (off the workers' critical path)
      float s_p = lo_f(d2), b_p = hi_f(d2);
      int   i_p = (int)(u32)d3;
      #pragma unroll
      for (int m = 1; m < 64; m <<= 1) {
        float s2 = __shfl_xor(s_p, m);
        float b2 = __shfl_xor(b_p, m);
        int   i2 = __shfl_xor(i_p, m);
        s_p += s2;
        if (b2 > b_p || (b2 == b_p && i2 < i_p)) { b_p = b2; i_p = i2; }
      }
      if (l == 0) { cw_s[wv] = s_p; cw_b[wv] = b_p; cw_i[wv] = i_p; }
      __syncthreads();
      if (tid == 0) {
        float s = cw_s[0], bv = cw_b[0]; int bi = cw_i[0];
        #pragma unroll
        for (int q = 1; q < 4; ++q) {
          s += cw_s[q];
          if (cw_b[q] > bv || (cw_b[q] == bv && cw_i[q] < bi)) { bv = cw_b[q]; bi = cw_i[q]; }
        }
        if (k >= 1) {
          out[k - 1]       = (float)bi;
          out[SEQ + k - 1] = bv - logf(s);
          if ((bi >> 2) == b) vis |= 1u << (bi & 3);
          if (k < SEQ) {
            u64 f = (u64)(u32)bi | ((u64)(u32)(k + 1) << 32);
            __hip_atomic_store(&flagP[par], f, __ATOMIC_RELEASE, AGENT);
          }
        }
      }
      if (k == SEQ) break;
    } else {
      if (k == SEQ) break;   // partials published; agg self-sufficient
      if (tid == 0) {
        u64 f = __hip_atomic_load(&flagH[par], __ATOMIC_RELAXED, AGENT);
        while ((u32)f != (u32)(k + 1)) {
          __builtin_amdgcn_s_sleep(1);
          f = __hip_atomic_load(&flagH[par], __ATOMIC_RELAXED, AGENT);
        }
      }
      __syncthreads();   // h_k ready for everyone
      __builtin_amdgcn_sched_barrier(0);
    }

    // ---- gather h_k via NORMAL CACHED loads (L2-amplified broadcast) ----
    hL[tid] = hist4[(size_t)k * 256 + tid];
    // next iteration's top __syncthreads orders these writes before reads
  }
}

extern "C" void kernel_launch(void* const* d_in, const int* in_sizes, int n_in,
                              void* d_out, int out_size, void* d_ws, size_t ws_size,
                              hipStream_t stream) {
  const float* X     = (const float*)d_in[0];
  const float* ENC   = (const float*)d_in[1];
  const float* W_ih  = (const float*)d_in[2];
  const float* W_hh  = (const float*)d_in[3];
  const float* b_ih  = (const float*)d_in[4];
  const float* b_hh  = (const float*)d_in[5];
  const float* W_out = (const float*)d_in[6];
  const float* b_out = (const float*)d_in[7];
  float* out = (float*)d_out;

  const int big_bytes = (16 * 256 + 1024 + 1024 + 256) * 16;  // 102400

  const size_t hist_bytes = (size_t)SEQ * HID * sizeof(float);   // 4 MB
  const size_t mbox_bytes = (size_t)2 * NB * sizeof(Mbox);       // 16 KB

  float* hist  = (float*)d_ws;
  Mbox*  mb    = (Mbox*)((char*)d_ws + hist_bytes);
  u64*   flags = (u64*)((char*)d_ws + hist_bytes + mbox_bytes);

  (void)hipFuncSetAttribute(
      reinterpret_cast<const void*>(&decoder_r5),
      hipFuncAttributeMaxDynamicSharedMemorySize, big_bytes);
  decoder_r5<<<NB, TPB, big_bytes, stream>>>(
      X, ENC, W_ih, W_hh, b_ih, b_hh, W_out, b_out, out,
      hist, mb, flags, flags + 2);
}